// Round 1
// baseline (745.228 us; speedup 1.0000x reference)
//
#include <hip/hip_runtime.h>

#define K_OFF   8
#define R_PAIRS 62500
#define N_IN    500000
#define N_OUT   125000
#define CIN     64
#define COUT    128
#define BN_EPS  1e-4f
#define TILES   8   // 64-row tiles per block chunk

typedef __bf16 bf16;
typedef __bf16 bf16x8 __attribute__((ext_vector_type(8)));
typedef float  f32x4  __attribute__((ext_vector_type(4)));

// ---------------- BN statistics: per-channel sum & sumsq ----------------
template<int C>
__global__ void bn_stats_kernel(const float* __restrict__ x, int n_rows,
                                float* __restrict__ sums /* [2C] */) {
    constexpr int CG = C / 4;
    int tid = blockIdx.x * blockDim.x + threadIdx.x;
    int nth = gridDim.x * blockDim.x;          // multiple of CG
    const float4* x4 = (const float4*)x;
    long n4 = (long)n_rows * CG;
    int cg = tid % CG;                          // constant channel-group per thread
    float s[4] = {0,0,0,0}, q[4] = {0,0,0,0};
    for (long i = tid; i < n4; i += nth) {
        float4 v = x4[i];
        float f[4] = {v.x, v.y, v.z, v.w};
        #pragma unroll
        for (int j = 0; j < 4; j++) { s[j] += f[j]; q[j] += f[j] * f[j]; }
    }
    __shared__ float acc[2 * C];
    for (int i = threadIdx.x; i < 2 * C; i += blockDim.x) acc[i] = 0.f;
    __syncthreads();
    #pragma unroll
    for (int j = 0; j < 4; j++) {
        atomicAdd(&acc[cg * 4 + j], s[j]);
        atomicAdd(&acc[C + cg * 4 + j], q[j]);
    }
    __syncthreads();
    for (int i = threadIdx.x; i < 2 * C; i += blockDim.x) atomicAdd(&sums[i], acc[i]);
}

template<int C>
__global__ void bn_finalize_kernel(const float* __restrict__ sums,
                                   const float* __restrict__ gamma,
                                   const float* __restrict__ beta,
                                   float inv_n, float* __restrict__ ss /* [2C] scale,shift */) {
    int c = threadIdx.x;
    if (c < C) {
        float m  = sums[c] * inv_n;
        float v  = sums[C + c] * inv_n - m * m;
        float sc = gamma[c] * rsqrtf(v + BN_EPS);
        ss[c]     = sc;
        ss[C + c] = beta[c] - m * sc;
    }
}

// ---------------- conv1 + conv2 fused (Cin=64, shared rulebook) ----------------
// grid: (ceil(R/512), 8). block: 256 = 4 waves.
// wave 0: W1 cols 0-63 -> y1 ; wave 1: W1 cols 64-127 -> y1
// wave 2: W2 cols 0-63 -> y2 ; wave 3: W2 cols 64-127 -> y2
__global__ __launch_bounds__(256) void conv12_kernel(
    const float* __restrict__ x,
    const float* __restrict__ W1, const float* __restrict__ W2,
    const int* __restrict__ in_idx, const int* __restrict__ out_idx,
    const float* __restrict__ ss1,
    float* __restrict__ y1, float* __restrict__ y2)
{
    int k    = blockIdx.y;
    int tid  = threadIdx.x;
    int wave = tid >> 6, lane = tid & 63;

    __shared__ bf16 As[64 * 64];       // 8 KB, XOR-swizzled
    __shared__ int  s_out[64];
    __shared__ float s_sc[64], s_sh[64];
    char* asb = (char*)As;

    if (tid < 64) { s_sc[tid] = ss1[tid]; s_sh[tid] = ss1[64 + tid]; }

    const float* Wk = ((wave & 2) ? W2 : W1) + (long)k * CIN * COUT;
    int nbase = (wave & 1) * 64;
    int l15 = lane & 15;
    int kr0 = (lane >> 4) * 8;

    // B fragments: load once per block, straight to VGPRs (W is L2-resident)
    bf16x8 bfrag[2][4];
    #pragma unroll
    for (int ks = 0; ks < 2; ks++) {
        #pragma unroll
        for (int nf = 0; nf < 4; nf++) {
            const float* p = Wk + (long)(ks * 32 + kr0) * COUT + nbase + nf * 16 + l15;
            bf16x8 b;
            #pragma unroll
            for (int j = 0; j < 8; j++) b[j] = (bf16)p[(long)j * COUT];
            bfrag[ks][nf] = b;
        }
    }

    const int* in_k  = in_idx  + k * R_PAIRS;
    const int* out_k = out_idx + k * R_PAIRS;
    float* ybase = (wave & 2) ? y2 : y1;

    int grow = tid >> 2;          // gather: 4 threads per row
    int gcol = (tid & 3) * 16;    // 16 floats each

    __syncthreads();              // s_sc/s_sh ready

    for (int t = 0; t < TILES; t++) {
        int pair0 = blockIdx.x * (TILES * 64) + t * 64;

        // ---- gather 64 rows of x, apply BN1+ReLU, bf16 into swizzled LDS ----
        {
            int p = pair0 + grow;
            bool valid = p < R_PAIRS;
            long src = valid ? (long)in_k[p] : 0;
            const float4* xr = (const float4*)(x + src * CIN + gcol);
            #pragma unroll
            for (int g = 0; g < 2; g++) {
                float4 va = make_float4(0, 0, 0, 0), vb = va;
                if (valid) { va = xr[g * 2]; vb = xr[g * 2 + 1]; }
                float f[8] = {va.x, va.y, va.z, va.w, vb.x, vb.y, vb.z, vb.w};
                bf16x8 h;
                #pragma unroll
                for (int j = 0; j < 8; j++) {
                    int c = gcol + g * 8 + j;
                    float val = f[j] * s_sc[c] + s_sh[c];
                    h[j] = (bf16)fmaxf(val, 0.f);
                }
                int byteoff = ((grow * 128) + (gcol + g * 8) * 2) ^ ((grow & 7) << 4);
                *(bf16x8*)(asb + byteoff) = h;
            }
        }
        if (tid < 64) {
            int p = pair0 + tid;
            s_out[tid] = (p < R_PAIRS) ? out_k[p] : -1;
        }
        __syncthreads();

        // ---- MFMA: [64 x 64] x [64 x 64-slice] ----
        f32x4 acc[4][4];
        #pragma unroll
        for (int m = 0; m < 4; m++)
            #pragma unroll
            for (int n = 0; n < 4; n++) acc[m][n] = (f32x4)(0.f);

        #pragma unroll
        for (int ks = 0; ks < 2; ks++) {
            bf16x8 af[4];
            #pragma unroll
            for (int m = 0; m < 4; m++) {
                int row = m * 16 + l15;
                int byteoff = (row * 128 + (ks * 32 + kr0) * 2) ^ ((row & 7) << 4);
                af[m] = *(bf16x8*)(asb + byteoff);
            }
            #pragma unroll
            for (int m = 0; m < 4; m++)
                #pragma unroll
                for (int nf = 0; nf < 4; nf++)
                    acc[m][nf] = __builtin_amdgcn_mfma_f32_16x16x32_bf16(
                        af[m], bfrag[ks][nf], acc[m][nf], 0, 0, 0);
        }

        // ---- scatter-add ----
        int rbase = (lane >> 4) * 4;
        #pragma unroll
        for (int m = 0; m < 4; m++) {
            #pragma unroll
            for (int j = 0; j < 4; j++) {
                int o = s_out[m * 16 + rbase + j];
                if (o >= 0) {
                    #pragma unroll
                    for (int nf = 0; nf < 4; nf++)
                        atomicAdd(&ybase[(long)o * COUT + nbase + nf * 16 + l15],
                                  acc[m][nf][j]);
                }
            }
        }
        __syncthreads();   // As/s_out reused next tile
    }
}

// ---------------- submanifold conv (Cin=128) ----------------
// wave w owns cols [w*32, w*32+32)
__global__ __launch_bounds__(256) void convs_kernel(
    const float* __restrict__ y1,
    const float* __restrict__ Ws,
    const int* __restrict__ in_idx, const int* __restrict__ out_idx,
    const float* __restrict__ ss2,
    float* __restrict__ out)
{
    int k    = blockIdx.y;
    int tid  = threadIdx.x;
    int wave = tid >> 6, lane = tid & 63;

    __shared__ bf16 As[64 * 128];     // 16 KB
    __shared__ int  s_out[64];
    __shared__ float s_sc[128], s_sh[128];
    char* asb = (char*)As;

    if (tid < 128) { s_sc[tid] = ss2[tid]; s_sh[tid] = ss2[128 + tid]; }

    const float* Wk = Ws + (long)k * COUT * COUT;
    int nbase = wave * 32;
    int l15 = lane & 15;
    int kr0 = (lane >> 4) * 8;

    bf16x8 bfrag[4][2];
    #pragma unroll
    for (int ks = 0; ks < 4; ks++) {
        #pragma unroll
        for (int nf = 0; nf < 2; nf++) {
            const float* p = Wk + (long)(ks * 32 + kr0) * COUT + nbase + nf * 16 + l15;
            bf16x8 b;
            #pragma unroll
            for (int j = 0; j < 8; j++) b[j] = (bf16)p[(long)j * COUT];
            bfrag[ks][nf] = b;
        }
    }

    const int* in_k  = in_idx  + k * R_PAIRS;
    const int* out_k = out_idx + k * R_PAIRS;

    int grow = tid >> 2;          // 4 threads per row
    int gcol = (tid & 3) * 32;    // 32 floats each

    __syncthreads();

    for (int t = 0; t < TILES; t++) {
        int pair0 = blockIdx.x * (TILES * 64) + t * 64;

        // ---- gather y1 rows, apply BN2+ReLU ----
        {
            int p = pair0 + grow;
            bool valid = p < R_PAIRS;
            long src = valid ? (long)in_k[p] : 0;
            const float4* yr = (const float4*)(y1 + src * COUT + gcol);
            #pragma unroll
            for (int g = 0; g < 4; g++) {
                float4 va = make_float4(0, 0, 0, 0), vb = va;
                if (valid) { va = yr[g * 2]; vb = yr[g * 2 + 1]; }
                float f[8] = {va.x, va.y, va.z, va.w, vb.x, vb.y, vb.z, vb.w};
                bf16x8 h;
                #pragma unroll
                for (int j = 0; j < 8; j++) {
                    int c = gcol + g * 8 + j;
                    float val = f[j] * s_sc[c] + s_sh[c];
                    h[j] = (bf16)fmaxf(val, 0.f);
                }
                int byteoff = (grow * 256 + (gcol + g * 8) * 2) ^ ((grow & 7) << 4);
                *(bf16x8*)(asb + byteoff) = h;
            }
        }
        if (tid < 64) {
            int p = pair0 + tid;
            s_out[tid] = (p < R_PAIRS) ? out_k[p] : -1;
        }
        __syncthreads();

        f32x4 acc[4][2];
        #pragma unroll
        for (int m = 0; m < 4; m++)
            #pragma unroll
            for (int n = 0; n < 2; n++) acc[m][n] = (f32x4)(0.f);

        #pragma unroll
        for (int ks = 0; ks < 4; ks++) {
            bf16x8 af[4];
            #pragma unroll
            for (int m = 0; m < 4; m++) {
                int row = m * 16 + l15;
                int byteoff = (row * 256 + (ks * 32 + kr0) * 2) ^ ((row & 7) << 4);
                af[m] = *(bf16x8*)(asb + byteoff);
            }
            #pragma unroll
            for (int m = 0; m < 4; m++)
                #pragma unroll
                for (int nf = 0; nf < 2; nf++)
                    acc[m][nf] = __builtin_amdgcn_mfma_f32_16x16x32_bf16(
                        af[m], bfrag[ks][nf], acc[m][nf], 0, 0, 0);
        }

        int rbase = (lane >> 4) * 4;
        #pragma unroll
        for (int m = 0; m < 4; m++) {
            #pragma unroll
            for (int j = 0; j < 4; j++) {
                int o = s_out[m * 16 + rbase + j];
                if (o >= 0) {
                    #pragma unroll
                    for (int nf = 0; nf < 2; nf++)
                        atomicAdd(&out[(long)o * COUT + nbase + nf * 16 + l15],
                                  acc[m][nf][j]);
                }
            }
        }
        __syncthreads();
    }
}

extern "C" void kernel_launch(void* const* d_in, const int* in_sizes, int n_in,
                              void* d_out, int out_size, void* d_ws, size_t ws_size,
                              hipStream_t stream) {
    const float* x       = (const float*)d_in[0];
    const float* gamma1  = (const float*)d_in[1];
    const float* beta1   = (const float*)d_in[2];
    const float* gamma2  = (const float*)d_in[3];
    const float* beta2   = (const float*)d_in[4];
    const float* W1      = (const float*)d_in[5];
    const float* Ws      = (const float*)d_in[6];
    const float* W2      = (const float*)d_in[7];
    const int*   in_idx1  = (const int*)d_in[8];
    const int*   out_idx1 = (const int*)d_in[9];
    const int*   in_idx_s = (const int*)d_in[10];
    const int*   out_idx_s= (const int*)d_in[11];

    float* out   = (float*)d_out;
    float* y1    = (float*)d_ws;                  // 125000*128 floats = 64 MB
    float* stats = y1 + (long)N_OUT * COUT;
    float* sums1 = stats;          // 128
    float* ss1   = stats + 128;    // 128
    float* sums2 = stats + 256;    // 256
    float* ss2   = stats + 512;    // 256

    hipMemsetAsync(d_out, 0, (size_t)N_OUT * COUT * 4, stream);
    hipMemsetAsync(d_ws,  0, (size_t)N_OUT * COUT * 4 + 768 * 4, stream);

    bn_stats_kernel<64><<<1024, 256, 0, stream>>>(x, N_IN, sums1);
    bn_finalize_kernel<64><<<1, 64, 0, stream>>>(sums1, gamma1, beta1, 1.f / N_IN, ss1);

    dim3 cgrid((R_PAIRS + TILES * 64 - 1) / (TILES * 64), K_OFF);   // (123, 8)
    conv12_kernel<<<cgrid, 256, 0, stream>>>(x, W1, W2, in_idx1, out_idx1, ss1, y1, out);

    bn_stats_kernel<128><<<1024, 256, 0, stream>>>(y1, N_OUT, sums2);
    bn_finalize_kernel<128><<<1, 128, 0, stream>>>(sums2, gamma2, beta2, 1.f / N_OUT, ss2);

    convs_kernel<<<cgrid, 256, 0, stream>>>(y1, Ws, in_idx_s, out_idx_s, ss2, out);
}

// Round 2
// 683.857 us; speedup vs baseline: 1.0897x; 1.0897x over previous
//
#include <hip/hip_runtime.h>

#define K_OFF   8
#define R_PAIRS 62500
#define NPAIRS  500000
#define N_IN    500000
#define N_OUT   125000
#define CIN     64
#define COUT    128
#define BN_EPS  1e-4f
#define NBINS   1000000      // K_OFF * N_OUT
#define SCAN_ELEMS 4096
#define NSB     245          // ceil(NBINS / SCAN_ELEMS)
#define ATILES  2
#define OLD_TILES 8

typedef __bf16 bf16;
typedef __bf16 bf16x2 __attribute__((ext_vector_type(2)));
typedef __bf16 bf16x4 __attribute__((ext_vector_type(4)));
typedef __bf16 bf16x8 __attribute__((ext_vector_type(8)));
typedef float  f32x4  __attribute__((ext_vector_type(4)));
typedef unsigned int u32;

// ==================== BN statistics ====================
template<int C>
__global__ void bn_stats_kernel(const float* __restrict__ x, int n_rows,
                                float* __restrict__ sums /* [2C] */) {
    constexpr int CG = C / 4;
    int tid = blockIdx.x * blockDim.x + threadIdx.x;
    int nth = gridDim.x * blockDim.x;
    const float4* x4 = (const float4*)x;
    long n4 = (long)n_rows * CG;
    int cg = tid % CG;
    float s[4] = {0,0,0,0}, q[4] = {0,0,0,0};
    for (long i = tid; i < n4; i += nth) {
        float4 v = x4[i];
        float f[4] = {v.x, v.y, v.z, v.w};
        #pragma unroll
        for (int j = 0; j < 4; j++) { s[j] += f[j]; q[j] += f[j] * f[j]; }
    }
    __shared__ float acc[2 * C];
    for (int i = threadIdx.x; i < 2 * C; i += blockDim.x) acc[i] = 0.f;
    __syncthreads();
    #pragma unroll
    for (int j = 0; j < 4; j++) {
        atomicAdd(&acc[cg * 4 + j], s[j]);
        atomicAdd(&acc[C + cg * 4 + j], q[j]);
    }
    __syncthreads();
    for (int i = threadIdx.x; i < 2 * C; i += blockDim.x) atomicAdd(&sums[i], acc[i]);
}

template<int C>
__global__ void bn_finalize_kernel(const float* __restrict__ sums,
                                   const float* __restrict__ gamma,
                                   const float* __restrict__ beta,
                                   float inv_n, float* __restrict__ ss) {
    int c = threadIdx.x;
    if (c < C) {
        float m  = sums[c] * inv_n;
        float v  = sums[C + c] * inv_n - m * m;
        float sc = gamma[c] * rsqrtf(v + BN_EPS);
        ss[c]     = sc;
        ss[C + c] = beta[c] - m * sc;
    }
}

// ==================== BN apply + ReLU -> bf16 ====================
// fp32 input
template<int C>
__global__ void bn_apply_f32_kernel(const float* __restrict__ x, const float* __restrict__ ss,
                                    bf16* __restrict__ xo, long items /* rows*C/8 */) {
    constexpr int CG = C / 8;
    long i = (long)blockIdx.x * blockDim.x + threadIdx.x;
    long stride = (long)gridDim.x * blockDim.x;   // multiple of CG
    int cg = (int)(i % CG);
    float sc[8], sh[8];
    #pragma unroll
    for (int j = 0; j < 8; j++) { sc[j] = ss[cg*8+j]; sh[j] = ss[C + cg*8+j]; }
    for (; i < items; i += stride) {
        const float4* p = (const float4*)(x + i * 8);
        float4 a = p[0], b = p[1];
        float f[8] = {a.x,a.y,a.z,a.w,b.x,b.y,b.z,b.w};
        bf16x8 h;
        #pragma unroll
        for (int j = 0; j < 8; j++) h[j] = (bf16)fmaxf(f[j]*sc[j] + sh[j], 0.f);
        *(bf16x8*)(xo + i * 8) = h;
    }
}
// bf16 input
template<int C>
__global__ void bn_apply_bf16_kernel(const bf16* __restrict__ x, const float* __restrict__ ss,
                                     bf16* __restrict__ xo, long items) {
    constexpr int CG = C / 8;
    long i = (long)blockIdx.x * blockDim.x + threadIdx.x;
    long stride = (long)gridDim.x * blockDim.x;
    int cg = (int)(i % CG);
    float sc[8], sh[8];
    #pragma unroll
    for (int j = 0; j < 8; j++) { sc[j] = ss[cg*8+j]; sh[j] = ss[C + cg*8+j]; }
    for (; i < items; i += stride) {
        bf16x8 v = *(const bf16x8*)(x + i * 8);
        bf16x8 h;
        #pragma unroll
        for (int j = 0; j < 8; j++) h[j] = (bf16)fmaxf((float)v[j]*sc[j] + sh[j], 0.f);
        *(bf16x8*)(xo + i * 8) = h;
    }
}

// ==================== counting sort: hist / scan / scatter ====================
__global__ void hist_kernel(const int* __restrict__ oidx, u32* __restrict__ counts, int CH) {
    int p = blockIdx.x * blockDim.x + threadIdx.x;
    int stride = gridDim.x * blockDim.x;
    for (; p < NPAIRS; p += stride) {
        int out = oidx[p];
        int k = p / R_PAIRS;
        int c = out / CH;
        int bin = c * (K_OFF * CH) + k * CH + (out - c * CH);
        atomicAdd(&counts[bin], 1u);
    }
}

__global__ void scan1_kernel(const u32* __restrict__ counts, u32* __restrict__ bsum) {
    __shared__ u32 sd[256];
    int tid = threadIdx.x;
    int base = blockIdx.x * SCAN_ELEMS + tid * 16;
    u32 s = 0;
    #pragma unroll
    for (int j = 0; j < 16; j++) { int i = base + j; if (i < NBINS) s += counts[i]; }
    sd[tid] = s; __syncthreads();
    for (int st = 128; st > 0; st >>= 1) { if (tid < st) sd[tid] += sd[tid + st]; __syncthreads(); }
    if (tid == 0) bsum[blockIdx.x] = sd[0];
}

__global__ void scan2_kernel(u32* __restrict__ bsum, u32* __restrict__ starts, int nb) {
    __shared__ u32 sd[256];
    int tid = threadIdx.x;
    u32 v = (tid < nb) ? bsum[tid] : 0;
    sd[tid] = v; __syncthreads();
    for (int st = 1; st < 256; st <<= 1) {
        u32 t = (tid >= st) ? sd[tid - st] : 0;
        __syncthreads();
        sd[tid] += t;
        __syncthreads();
    }
    if (tid < nb) bsum[tid] = sd[tid] - v;     // exclusive
    if (tid == 255) starts[NBINS] = sd[255];   // total
}

__global__ void scan3_kernel(const u32* __restrict__ counts, const u32* __restrict__ bsum,
                             u32* __restrict__ starts) {
    __shared__ u32 sd[256];
    int tid = threadIdx.x;
    int base = blockIdx.x * SCAN_ELEMS + tid * 16;
    u32 v[16]; u32 s = 0;
    #pragma unroll
    for (int j = 0; j < 16; j++) { int i = base + j; v[j] = (i < NBINS) ? counts[i] : 0; s += v[j]; }
    sd[tid] = s; __syncthreads();
    for (int st = 1; st < 256; st <<= 1) {
        u32 t = (tid >= st) ? sd[tid - st] : 0;
        __syncthreads();
        sd[tid] += t;
        __syncthreads();
    }
    u32 run = bsum[blockIdx.x] + sd[tid] - s;
    #pragma unroll
    for (int j = 0; j < 16; j++) { int i = base + j; if (i < NBINS) starts[i] = run; run += v[j]; }
}

__global__ void scatter_kernel(const int* __restrict__ oidx, const u32* __restrict__ starts,
                               u32* __restrict__ cursor, u32* __restrict__ perm, int CH) {
    int p = blockIdx.x * blockDim.x + threadIdx.x;
    int stride = gridDim.x * blockDim.x;
    for (; p < NPAIRS; p += stride) {
        int out = oidx[p];
        int k = p / R_PAIRS;
        int c = out / CH;
        int bin = c * (K_OFF * CH) + k * CH + (out - c * CH);
        u32 pos = starts[bin] + atomicAdd(&cursor[bin], 1u);
        perm[pos] = (u32)p;
    }
}

// ==================== conv12 phase A: gather-GEMM -> bf16 temp ====================
// grid (gridx, 8). Wave w: cols [ (w&1)*64 + (w&2?128:0) .. +64 ) of 256-wide temp row.
__global__ __launch_bounds__(256) void convA12_kernel(
    const bf16* __restrict__ x1, const float* __restrict__ W1, const float* __restrict__ W2,
    const int* __restrict__ iidx, const u32* __restrict__ perm, const u32* __restrict__ starts,
    bf16* __restrict__ temp, int chunk, int CH)
{
    int k    = blockIdx.y;
    int tid  = threadIdx.x;
    int wave = tid >> 6, lane = tid & 63;

    u32 seg_lo = starts[((u32)chunk * K_OFF + k) * CH];
    u32 seg_hi = starts[((u32)chunk * K_OFF + k + 1) * CH];
    u32 ntiles = (seg_hi - seg_lo + 63) >> 6;
    u32 t0 = blockIdx.x * ATILES;
    if (t0 >= ntiles) return;
    u32 chunk_base = starts[(u32)chunk * K_OFF * CH];

    __shared__ bf16 As[64 * 64];
    char* asb = (char*)As;

    int l15 = lane & 15;
    int kr0 = (lane >> 4) * 8;
    const float* Wk = ((wave & 2) ? W2 : W1) + (long)k * CIN * COUT;
    int nbase = (wave & 1) * 64;
    int wcol  = nbase + ((wave & 2) ? 128 : 0);

    bf16x8 bfrag[2][4];
    #pragma unroll
    for (int ks = 0; ks < 2; ks++)
        #pragma unroll
        for (int nf = 0; nf < 4; nf++) {
            const float* p = Wk + (long)(ks * 32 + kr0) * COUT + nbase + nf * 16 + l15;
            bf16x8 b;
            #pragma unroll
            for (int j = 0; j < 8; j++) b[j] = (bf16)p[(long)j * COUT];
            bfrag[ks][nf] = b;
        }

    int grow = tid >> 2, gpart = tid & 3;
    int rbase = (lane >> 4) * 4;

    for (int t = 0; t < ATILES; t++) {
        u32 tile = t0 + t;
        if (tile >= ntiles) break;
        u32 pos0 = seg_lo + tile * 64;

        // gather 64 rows of x1 (bf16, 128B each) into swizzled LDS
        {
            u32 p = pos0 + grow;
            u32 pair = (p < seg_hi) ? perm[p] : 0u;
            int in = iidx[pair];
            const char* src = (const char*)(x1 + (long)in * CIN) + gpart * 32;
            int4 a = *(const int4*)src;
            int4 b = *(const int4*)(src + 16);
            int boff0 = (grow * 128 + gpart * 32)      ^ ((grow & 7) << 4);
            int boff1 = (grow * 128 + gpart * 32 + 16) ^ ((grow & 7) << 4);
            *(int4*)(asb + boff0) = a;
            *(int4*)(asb + boff1) = b;
        }
        __syncthreads();

        f32x4 acc[4][4];
        #pragma unroll
        for (int m = 0; m < 4; m++)
            #pragma unroll
            for (int n = 0; n < 4; n++) acc[m][n] = (f32x4)(0.f);

        #pragma unroll
        for (int ks = 0; ks < 2; ks++) {
            bf16x8 af[4];
            #pragma unroll
            for (int m = 0; m < 4; m++) {
                int row = m * 16 + l15;
                int boff = (row * 128 + (ks * 32 + kr0) * 2) ^ ((row & 7) << 4);
                af[m] = *(bf16x8*)(asb + boff);
            }
            #pragma unroll
            for (int m = 0; m < 4; m++)
                #pragma unroll
                for (int nf = 0; nf < 4; nf++)
                    acc[m][nf] = __builtin_amdgcn_mfma_f32_16x16x32_bf16(
                        af[m], bfrag[ks][nf], acc[m][nf], 0, 0, 0);
        }

        #pragma unroll
        for (int m = 0; m < 4; m++) {
            #pragma unroll
            for (int j = 0; j < 4; j++) {
                u32 pos = pos0 + m * 16 + rbase + j;
                if (pos < seg_hi) {
                    bf16* trow = temp + (size_t)(pos - chunk_base) * 256;
                    #pragma unroll
                    for (int nf = 0; nf < 4; nf++)
                        trow[wcol + nf * 16 + l15] = (bf16)acc[m][nf][j];
                }
            }
        }
        __syncthreads();
    }
}

// ==================== conv12 phase B: segmented sum -> y1(bf16)+out, fused BN2 stats ====
__global__ __launch_bounds__(256) void convB12_kernel(
    const bf16* __restrict__ temp, const u32* __restrict__ starts,
    bf16* __restrict__ y1, float* __restrict__ out, float* __restrict__ sums2,
    int chunk, int CH)
{
    __shared__ float bnacc[256];
    int tid = threadIdx.x;
    bnacc[tid] = 0.f;
    __syncthreads();
    int lane = tid & 63;
    int wid = blockIdx.x * 4 + (tid >> 6);
    int nw  = gridDim.x * 4;
    u32 chunk_base = starts[(u32)chunk * K_OFF * CH];
    float bs[4] = {0,0,0,0}, bq[4] = {0,0,0,0};

    for (int ol = wid; ol < CH; ol += nw) {
        float a[4] = {0,0,0,0};
        #pragma unroll
        for (int k = 0; k < K_OFF; k++) {
            u32 bin = ((u32)chunk * K_OFF + k) * CH + ol;
            u32 s = starts[bin], e = starts[bin + 1];
            for (u32 pos = s; pos < e; pos++) {
                bf16x4 v = *(const bf16x4*)(temp + (size_t)(pos - chunk_base) * 256 + lane * 4);
                #pragma unroll
                for (int j = 0; j < 4; j++) a[j] += (float)v[j];
            }
        }
        long o = (long)chunk * CH + ol;
        if (lane < 32) {
            bf16x4 h;
            #pragma unroll
            for (int j = 0; j < 4; j++) {
                h[j] = (bf16)a[j];
                bs[j] += a[j]; bq[j] += a[j] * a[j];
            }
            *(bf16x4*)(y1 + o * COUT + lane * 4) = h;
        } else {
            *(float4*)(out + o * COUT + (lane - 32) * 4) = make_float4(a[0], a[1], a[2], a[3]);
        }
    }
    if (lane < 32) {
        #pragma unroll
        for (int j = 0; j < 4; j++) {
            atomicAdd(&bnacc[lane * 4 + j], bs[j]);
            atomicAdd(&bnacc[128 + lane * 4 + j], bq[j]);
        }
    }
    __syncthreads();
    atomicAdd(&sums2[tid], bnacc[tid]);
}

// ==================== submanifold conv phase A ====================
__global__ __launch_bounds__(256) void convAs_kernel(
    const bf16* __restrict__ y1b, const float* __restrict__ Ws,
    const int* __restrict__ iidx, const u32* __restrict__ perm, const u32* __restrict__ starts,
    bf16* __restrict__ temp, int chunk, int CH)
{
    int k    = blockIdx.y;
    int tid  = threadIdx.x;
    int wave = tid >> 6, lane = tid & 63;

    u32 seg_lo = starts[((u32)chunk * K_OFF + k) * CH];
    u32 seg_hi = starts[((u32)chunk * K_OFF + k + 1) * CH];
    u32 ntiles = (seg_hi - seg_lo + 63) >> 6;
    u32 t0 = blockIdx.x * ATILES;
    if (t0 >= ntiles) return;
    u32 chunk_base = starts[(u32)chunk * K_OFF * CH];

    __shared__ bf16 As[64 * 128];
    char* asb = (char*)As;

    int l15 = lane & 15;
    int kr0 = (lane >> 4) * 8;
    const float* Wk = Ws + (long)k * COUT * COUT;
    int nbase = wave * 32;

    bf16x8 bfrag[4][2];
    #pragma unroll
    for (int ks = 0; ks < 4; ks++)
        #pragma unroll
        for (int nf = 0; nf < 2; nf++) {
            const float* p = Wk + (long)(ks * 32 + kr0) * COUT + nbase + nf * 16 + l15;
            bf16x8 b;
            #pragma unroll
            for (int j = 0; j < 8; j++) b[j] = (bf16)p[(long)j * COUT];
            bfrag[ks][nf] = b;
        }

    int grow = tid >> 2, gpart = tid & 3;
    int rbase = (lane >> 4) * 4;

    for (int t = 0; t < ATILES; t++) {
        u32 tile = t0 + t;
        if (tile >= ntiles) break;
        u32 pos0 = seg_lo + tile * 64;

        {
            u32 p = pos0 + grow;
            u32 pair = (p < seg_hi) ? perm[p] : 0u;
            int in = iidx[pair];
            const char* src = (const char*)(y1b + (long)in * COUT) + gpart * 64;
            #pragma unroll
            for (int q = 0; q < 4; q++) {
                int4 a = *(const int4*)(src + q * 16);
                int boff = (grow * 256 + gpart * 64 + q * 16) ^ ((grow & 7) << 4);
                *(int4*)(asb + boff) = a;
            }
        }
        __syncthreads();

        f32x4 acc[4][2];
        #pragma unroll
        for (int m = 0; m < 4; m++)
            #pragma unroll
            for (int n = 0; n < 2; n++) acc[m][n] = (f32x4)(0.f);

        #pragma unroll
        for (int ks = 0; ks < 4; ks++) {
            bf16x8 af[4];
            #pragma unroll
            for (int m = 0; m < 4; m++) {
                int row = m * 16 + l15;
                int boff = (row * 256 + (ks * 32 + kr0) * 2) ^ ((row & 7) << 4);
                af[m] = *(bf16x8*)(asb + boff);
            }
            #pragma unroll
            for (int m = 0; m < 4; m++)
                #pragma unroll
                for (int nf = 0; nf < 2; nf++)
                    acc[m][nf] = __builtin_amdgcn_mfma_f32_16x16x32_bf16(
                        af[m], bfrag[ks][nf], acc[m][nf], 0, 0, 0);
        }

        #pragma unroll
        for (int m = 0; m < 4; m++) {
            #pragma unroll
            for (int j = 0; j < 4; j++) {
                u32 pos = pos0 + m * 16 + rbase + j;
                if (pos < seg_hi) {
                    bf16* trow = temp + (size_t)(pos - chunk_base) * 128;
                    #pragma unroll
                    for (int nf = 0; nf < 2; nf++)
                        trow[nbase + nf * 16 + l15] = (bf16)acc[m][nf][j];
                }
            }
        }
        __syncthreads();
    }
}

// ==================== submanifold conv phase B: segmented sum, RMW into out ========
__global__ __launch_bounds__(256) void convBs_kernel(
    const bf16* __restrict__ temp, const u32* __restrict__ starts,
    float* __restrict__ out, int chunk, int CH)
{
    int tid = threadIdx.x;
    int lane = tid & 63;
    int wid = blockIdx.x * 4 + (tid >> 6);
    int nw  = gridDim.x * 4;
    u32 chunk_base = starts[(u32)chunk * K_OFF * CH];

    for (int ol = wid; ol < CH; ol += nw) {
        float a0 = 0.f, a1 = 0.f;
        #pragma unroll
        for (int k = 0; k < K_OFF; k++) {
            u32 bin = ((u32)chunk * K_OFF + k) * CH + ol;
            u32 s = starts[bin], e = starts[bin + 1];
            for (u32 pos = s; pos < e; pos++) {
                bf16x2 v = *(const bf16x2*)(temp + (size_t)(pos - chunk_base) * 128 + lane * 2);
                a0 += (float)v[0]; a1 += (float)v[1];
            }
        }
        long o = (long)chunk * CH + ol;
        float* po = out + o * COUT + lane * 2;
        po[0] += a0; po[1] += a1;
    }
}

// ==================== fallback (round-1 atomic path) ====================
__global__ __launch_bounds__(256) void conv12_atomic_kernel(
    const float* __restrict__ x,
    const float* __restrict__ W1, const float* __restrict__ W2,
    const int* __restrict__ in_idx, const int* __restrict__ out_idx,
    const float* __restrict__ ss1,
    float* __restrict__ y1, float* __restrict__ y2)
{
    int k    = blockIdx.y;
    int tid  = threadIdx.x;
    int wave = tid >> 6, lane = tid & 63;

    __shared__ bf16 As[64 * 64];
    __shared__ int  s_out[64];
    __shared__ float s_sc[64], s_sh[64];
    char* asb = (char*)As;

    if (tid < 64) { s_sc[tid] = ss1[tid]; s_sh[tid] = ss1[64 + tid]; }

    const float* Wk = ((wave & 2) ? W2 : W1) + (long)k * CIN * COUT;
    int nbase = (wave & 1) * 64;
    int l15 = lane & 15;
    int kr0 = (lane >> 4) * 8;

    bf16x8 bfrag[2][4];
    #pragma unroll
    for (int ks = 0; ks < 2; ks++)
        #pragma unroll
        for (int nf = 0; nf < 4; nf++) {
            const float* p = Wk + (long)(ks * 32 + kr0) * COUT + nbase + nf * 16 + l15;
            bf16x8 b;
            #pragma unroll
            for (int j = 0; j < 8; j++) b[j] = (bf16)p[(long)j * COUT];
            bfrag[ks][nf] = b;
        }

    const int* in_k  = in_idx  + k * R_PAIRS;
    const int* out_k = out_idx + k * R_PAIRS;
    float* ybase = (wave & 2) ? y2 : y1;

    int grow = tid >> 2;
    int gcol = (tid & 3) * 16;

    __syncthreads();

    for (int t = 0; t < OLD_TILES; t++) {
        int pair0 = blockIdx.x * (OLD_TILES * 64) + t * 64;
        {
            int p = pair0 + grow;
            bool valid = p < R_PAIRS;
            long src = valid ? (long)in_k[p] : 0;
            const float4* xr = (const float4*)(x + src * CIN + gcol);
            #pragma unroll
            for (int g = 0; g < 2; g++) {
                float4 va = make_float4(0, 0, 0, 0), vb = va;
                if (valid) { va = xr[g * 2]; vb = xr[g * 2 + 1]; }
                float f[8] = {va.x, va.y, va.z, va.w, vb.x, vb.y, vb.z, vb.w};
                bf16x8 h;
                #pragma unroll
                for (int j = 0; j < 8; j++) {
                    int c = gcol + g * 8 + j;
                    h[j] = (bf16)fmaxf(f[j] * s_sc[c] + s_sh[c], 0.f);
                }
                int boff = ((grow * 128) + (gcol + g * 8) * 2) ^ ((grow & 7) << 4);
                *(bf16x8*)(asb + boff) = h;
            }
        }
        if (tid < 64) {
            int p = pair0 + tid;
            s_out[tid] = (p < R_PAIRS) ? out_k[p] : -1;
        }
        __syncthreads();

        f32x4 acc[4][4];
        #pragma unroll
        for (int m = 0; m < 4; m++)
            #pragma unroll
            for (int n = 0; n < 4; n++) acc[m][n] = (f32x4)(0.f);

        #pragma unroll
        for (int ks = 0; ks < 2; ks++) {
            bf16x8 af[4];
            #pragma unroll
            for (int m = 0; m < 4; m++) {
                int row = m * 16 + l15;
                int boff = (row * 128 + (ks * 32 + kr0) * 2) ^ ((row & 7) << 4);
                af[m] = *(bf16x8*)(asb + boff);
            }
            #pragma unroll
            for (int m = 0; m < 4; m++)
                #pragma unroll
                for (int nf = 0; nf < 4; nf++)
                    acc[m][nf] = __builtin_amdgcn_mfma_f32_16x16x32_bf16(
                        af[m], bfrag[ks][nf], acc[m][nf], 0, 0, 0);
        }

        int rbase = (lane >> 4) * 4;
        #pragma unroll
        for (int m = 0; m < 4; m++)
            #pragma unroll
            for (int j = 0; j < 4; j++) {
                int o = s_out[m * 16 + rbase + j];
                if (o >= 0)
                    #pragma unroll
                    for (int nf = 0; nf < 4; nf++)
                        atomicAdd(&ybase[(long)o * COUT + nbase + nf * 16 + l15],
                                  acc[m][nf][j]);
            }
        __syncthreads();
    }
}

__global__ __launch_bounds__(256) void convs_atomic_kernel(
    const float* __restrict__ y1,
    const float* __restrict__ Ws,
    const int* __restrict__ in_idx, const int* __restrict__ out_idx,
    const float* __restrict__ ss2,
    float* __restrict__ out)
{
    int k    = blockIdx.y;
    int tid  = threadIdx.x;
    int wave = tid >> 6, lane = tid & 63;

    __shared__ bf16 As[64 * 128];
    __shared__ int  s_out[64];
    __shared__ float s_sc[128], s_sh[128];
    char* asb = (char*)As;

    if (tid < 128) { s_sc[tid] = ss2[tid]; s_sh[tid] = ss2[128 + tid]; }

    const float* Wk = Ws + (long)k * COUT * COUT;
    int nbase = wave * 32;
    int l15 = lane & 15;
    int kr0 = (lane >> 4) * 8;

    bf16x8 bfrag[4][2];
    #pragma unroll
    for (int ks = 0; ks < 4; ks++)
        #pragma unroll
        for (int nf = 0; nf < 2; nf++) {
            const float* p = Wk + (long)(ks * 32 + kr0) * COUT + nbase + nf * 16 + l15;
            bf16x8 b;
            #pragma unroll
            for (int j = 0; j < 8; j++) b[j] = (bf16)p[(long)j * COUT];
            bfrag[ks][nf] = b;
        }

    const int* in_k  = in_idx  + k * R_PAIRS;
    const int* out_k = out_idx + k * R_PAIRS;

    int grow = tid >> 2;
    int gcol = (tid & 3) * 32;

    __syncthreads();

    for (int t = 0; t < OLD_TILES; t++) {
        int pair0 = blockIdx.x * (OLD_TILES * 64) + t * 64;
        {
            int p = pair0 + grow;
            bool valid = p < R_PAIRS;
            long src = valid ? (long)in_k[p] : 0;
            const float4* yr = (const float4*)(y1 + src * COUT + gcol);
            #pragma unroll
            for (int g = 0; g < 4; g++) {
                float4 va = make_float4(0, 0, 0, 0), vb = va;
                if (valid) { va = yr[g * 2]; vb = yr[g * 2 + 1]; }
                float f[8] = {va.x, va.y, va.z, va.w, vb.x, vb.y, vb.z, vb.w};
                bf16x8 h;
                #pragma unroll
                for (int j = 0; j < 8; j++) {
                    int c = gcol + g * 8 + j;
                    h[j] = (bf16)fmaxf(f[j] * s_sc[c] + s_sh[c], 0.f);
                }
                int boff = (grow * 256 + (gcol + g * 8) * 2) ^ ((grow & 7) << 4);
                *(bf16x8*)(asb + boff) = h;
            }
        }
        if (tid < 64) {
            int p = pair0 + tid;
            s_out[tid] = (p < R_PAIRS) ? out_k[p] : -1;
        }
        __syncthreads();

        f32x4 acc[4][2];
        #pragma unroll
        for (int m = 0; m < 4; m++)
            #pragma unroll
            for (int n = 0; n < 2; n++) acc[m][n] = (f32x4)(0.f);

        #pragma unroll
        for (int ks = 0; ks < 4; ks++) {
            bf16x8 af[4];
            #pragma unroll
            for (int m = 0; m < 4; m++) {
                int row = m * 16 + l15;
                int boff = (row * 256 + (ks * 32 + kr0) * 2) ^ ((row & 7) << 4);
                af[m] = *(bf16x8*)(asb + boff);
            }
            #pragma unroll
            for (int m = 0; m < 4; m++)
                #pragma unroll
                for (int nf = 0; nf < 2; nf++)
                    acc[m][nf] = __builtin_amdgcn_mfma_f32_16x16x32_bf16(
                        af[m], bfrag[ks][nf], acc[m][nf], 0, 0, 0);
        }

        int rbase = (lane >> 4) * 4;
        #pragma unroll
        for (int m = 0; m < 4; m++)
            #pragma unroll
            for (int j = 0; j < 4; j++) {
                int o = s_out[m * 16 + rbase + j];
                if (o >= 0)
                    #pragma unroll
                    for (int nf = 0; nf < 2; nf++)
                        atomicAdd(&out[(long)o * COUT + nbase + nf * 16 + l15],
                                  acc[m][nf][j]);
            }
        __syncthreads();
    }
}

// ==================== host ====================
extern "C" void kernel_launch(void* const* d_in, const int* in_sizes, int n_in,
                              void* d_out, int out_size, void* d_ws, size_t ws_size,
                              hipStream_t stream) {
    const float* x       = (const float*)d_in[0];
    const float* gamma1  = (const float*)d_in[1];
    const float* beta1   = (const float*)d_in[2];
    const float* gamma2  = (const float*)d_in[3];
    const float* beta2   = (const float*)d_in[4];
    const float* W1      = (const float*)d_in[5];
    const float* Ws      = (const float*)d_in[6];
    const float* W2      = (const float*)d_in[7];
    const int*   in_idx1   = (const int*)d_in[8];
    const int*   out_idx1  = (const int*)d_in[9];
    const int*   in_idx_s  = (const int*)d_in[10];
    const int*   out_idx_s = (const int*)d_in[11];

    float* out = (float*)d_out;
    char*  ws  = (char*)d_ws;

    auto a256 = [](size_t v) { return (v + 255) & ~(size_t)255; };

    // layout (temp last, size depends on chunk count C)
    size_t off_y1     = 0;                                  // bf16 y1: 32 MB
    size_t off_sums   = a256(off_y1 + 32000000);            // 4 KB stats
    size_t off_x1     = a256(off_sums + 4096);              // bf16 x1: 64 MB
    size_t off_y1b    = a256(off_x1 + 64000000);            // bf16 y1b: 32 MB
    size_t off_counts = a256(off_y1b + 32000000);           // 4 MB
    size_t off_st1    = a256(off_counts + 4000000);         // 4 MB + 4
    size_t off_st2    = a256(off_st1 + 4 * (NBINS + 1));
    size_t off_p1     = a256(off_st2 + 4 * (NBINS + 1));    // 2 MB
    size_t off_p2     = a256(off_p1 + 4 * NPAIRS);
    size_t off_temp   = a256(off_p2 + 4 * NPAIRS);

    int C = 0; size_t cap = 0;
    const int cands[3] = {2, 4, 8};
    for (int ci = 0; ci < 3; ci++) {
        size_t capr = (size_t)(NPAIRS / cands[ci]) + 16384;
        if (off_temp + capr * 512 <= ws_size) { C = cands[ci]; cap = capr; break; }
    }

    if (C == 0) {
        // -------- fallback: round-1 atomic path (needs only 64 MB + 4 KB) --------
        float* y1f   = (float*)ws;
        float* stats = y1f + (long)N_OUT * COUT;
        float* sums1 = stats;
        float* ss1   = stats + 128;
        float* sums2 = stats + 256;
        float* ss2   = stats + 512;

        hipMemsetAsync(d_out, 0, (size_t)N_OUT * COUT * 4, stream);
        hipMemsetAsync(d_ws,  0, (size_t)N_OUT * COUT * 4 + 768 * 4, stream);

        bn_stats_kernel<64><<<1024, 256, 0, stream>>>(x, N_IN, sums1);
        bn_finalize_kernel<64><<<1, 64, 0, stream>>>(sums1, gamma1, beta1, 1.f / N_IN, ss1);

        dim3 cgrid((R_PAIRS + OLD_TILES * 64 - 1) / (OLD_TILES * 64), K_OFF);
        conv12_atomic_kernel<<<cgrid, 256, 0, stream>>>(x, W1, W2, in_idx1, out_idx1, ss1, y1f, out);

        bn_stats_kernel<128><<<1024, 256, 0, stream>>>(y1f, N_OUT, sums2);
        bn_finalize_kernel<128><<<1, 128, 0, stream>>>(sums2, gamma2, beta2, 1.f / N_OUT, ss2);

        convs_atomic_kernel<<<cgrid, 256, 0, stream>>>(y1f, Ws, in_idx_s, out_idx_s, ss2, out);
        return;
    }

    int CH = N_OUT / C;

    bf16* y1     = (bf16*)(ws + off_y1);
    float* sums1 = (float*)(ws + off_sums);        // [256]
    float* ss1   = sums1 + 256;                    // [128]
    float* sums2 = ss1 + 128;                      // [256]
    float* ss2   = sums2 + 256;                    // [256]
    bf16* x1     = (bf16*)(ws + off_x1);
    bf16* y1b    = (bf16*)(ws + off_y1b);
    u32*  counts = (u32*)(ws + off_counts);
    u32*  st1    = (u32*)(ws + off_st1);
    u32*  st2    = (u32*)(ws + off_st2);
    u32*  p1     = (u32*)(ws + off_p1);
    u32*  p2     = (u32*)(ws + off_p2);
    bf16* temp   = (bf16*)(ws + off_temp);
    u32*  bsum   = counts;   // reuse? NO — scan reads counts. Use tail of sums region:
    // bsum needs NSB u32 = 980 B; place after ss2 within the 4 KB stats page? too small.
    // carve from perm2 tail is unsafe; instead place bsum in temp region (temp unused during sort).
    bsum = (u32*)(ws + off_temp);

    // ---- init ----
    hipMemsetAsync(sums1, 0, 4096, stream);   // whole stats page (sums1/ss1/sums2/ss2)
    hipMemsetAsync(counts, 0, 4000000, stream);

    // ---- BN1 stats + apply -> x1 (bf16) ----
    bn_stats_kernel<64><<<1024, 256, 0, stream>>>(x, N_IN, sums1);
    bn_finalize_kernel<64><<<1, 64, 0, stream>>>(sums1, gamma1, beta1, 1.f / N_IN, ss1);
    bn_apply_f32_kernel<64><<<4096, 256, 0, stream>>>(x, ss1, x1, (long)N_IN * CIN / 8);

    // ---- sort 1 (conv1 rulebook by (chunk,k,out)) ----
    hist_kernel<<<512, 256, 0, stream>>>(out_idx1, counts, CH);
    scan1_kernel<<<NSB, 256, 0, stream>>>(counts, bsum);
    scan2_kernel<<<1, 256, 0, stream>>>(bsum, st1, NSB);
    scan3_kernel<<<NSB, 256, 0, stream>>>(counts, bsum, st1);
    hipMemsetAsync(counts, 0, 4000000, stream);
    scatter_kernel<<<512, 256, 0, stream>>>(out_idx1, st1, counts, p1, CH);

    // ---- conv1+conv2 per chunk ----
    {
        int maxseg = NPAIRS / (K_OFF * C);
        maxseg += maxseg / 12 + 512;
        int gridx = ((maxseg + 63) / 64 + ATILES - 1) / ATILES;
        dim3 gA(gridx, K_OFF);
        for (int c = 0; c < C; c++) {
            convA12_kernel<<<gA, 256, 0, stream>>>(x1, W1, W2, in_idx1, p1, st1, temp, c, CH);
            convB12_kernel<<<2048, 256, 0, stream>>>(temp, st1, y1, out, sums2, c, CH);
        }
    }

    // ---- BN2 finalize + apply -> y1b (bf16) ----
    bn_finalize_kernel<128><<<1, 128, 0, stream>>>(sums2, gamma2, beta2, 1.f / N_OUT, ss2);
    bn_apply_bf16_kernel<128><<<2048, 256, 0, stream>>>(y1, ss2, y1b, (long)N_OUT * COUT / 8);

    // ---- sort 2 (submanifold rulebook) ----
    hipMemsetAsync(counts, 0, 4000000, stream);
    hist_kernel<<<512, 256, 0, stream>>>(out_idx_s, counts, CH);
    scan1_kernel<<<NSB, 256, 0, stream>>>(counts, bsum);
    scan2_kernel<<<1, 256, 0, stream>>>(bsum, st2, NSB);
    scan3_kernel<<<NSB, 256, 0, stream>>>(counts, bsum, st2);
    hipMemsetAsync(counts, 0, 4000000, stream);
    scatter_kernel<<<512, 256, 0, stream>>>(out_idx_s, st2, counts, p2, CH);

    // ---- submanifold conv per chunk ----
    {
        int maxseg = NPAIRS / (K_OFF * C);
        maxseg += maxseg / 12 + 512;
        int gridx = ((maxseg + 63) / 64 + ATILES - 1) / ATILES;
        dim3 gA(gridx, K_OFF);
        for (int c = 0; c < C; c++) {
            convAs_kernel<<<gA, 256, 0, stream>>>(y1b, Ws, in_idx_s, p2, st2, temp, c, CH);
            convBs_kernel<<<2048, 256, 0, stream>>>(temp, st2, out, c, CH);
        }
    }
}